// Round 1
// baseline (290.272 us; speedup 1.0000x reference)
//
#include <hip/hip_runtime.h>
#include <hip/hip_bf16.h>

// Problem constants (from reference): x [2,1024,1024] fp32
#define NTOK 2048
#define DIM  1024
#define DEXP 512
#define NEXP 8
#define DSH  1024          // shared expert width
#define KH   5120          // DSH + NEXP*DEXP : concat width of H / rows of down-proj

typedef __hip_bfloat16 bf16;
typedef __attribute__((ext_vector_type(8))) short bf16x8;   // 8 bf16 = 4 VGPRs (MFMA A/B frag)
typedef __attribute__((ext_vector_type(4))) float floatx4;  // MFMA C/D frag

// ---------------------------------------------------------------------------
// fp32 -> bf16 flat cast (x), 4 elements/thread
// ---------------------------------------------------------------------------
__global__ __launch_bounds__(256) void cast_x_kernel(const float* __restrict__ src,
                                                     bf16* __restrict__ dst, int n4) {
    int i = blockIdx.x * 256 + threadIdx.x;
    if (i >= n4) return;
    float4 v = ((const float4*)src)[i];
    struct B4 { bf16 a, b, c, d; };
    B4 o{__float2bfloat16(v.x), __float2bfloat16(v.y),
         __float2bfloat16(v.z), __float2bfloat16(v.w)};
    ((B4*)dst)[i] = o;
}

// ---------------------------------------------------------------------------
// Transpose-cast: src fp32 [R,C] (+z*srcZ) -> dst bf16 [C,R] at
// dst + dstBase + z*dstZstep, row stride dstStride. 32x32 LDS tile.
// ---------------------------------------------------------------------------
__global__ __launch_bounds__(256) void tcast(const float* __restrict__ src,
                                             bf16* __restrict__ dst,
                                             int R, int C,
                                             long srcZ, long dstBase, long dstZstep,
                                             int dstStride) {
    __shared__ float t[32][33];
    const float* s = src + (long)blockIdx.z * srcZ;
    bf16* d = dst + dstBase + (long)blockIdx.z * dstZstep;
    int c0 = blockIdx.x * 32, r0 = blockIdx.y * 32;
    int tx = threadIdx.x & 31, ty = threadIdx.x >> 5;   // 32x8
#pragma unroll
    for (int i = 0; i < 4; i++)
        t[ty + i * 8][tx] = s[(long)(r0 + ty + i * 8) * C + c0 + tx];
    __syncthreads();
#pragma unroll
    for (int i = 0; i < 4; i++)
        d[(long)(c0 + ty + i * 8) * dstStride + r0 + tx] =
            __float2bfloat16(t[tx][ty + i * 8]);
}

// ---------------------------------------------------------------------------
// Gating: one wave per token. fp32 logits -> softmax -> top-2 -> c[N,8]
// (c[n,e] = softmax prob if e in top2 else 0; fp32 so top-k matches reference)
// ---------------------------------------------------------------------------
__global__ __launch_bounds__(256) void gate_kernel(const float* __restrict__ x,
                                                   const float* __restrict__ Wg,
                                                   float* __restrict__ c) {
    int t = blockIdx.x * 4 + (threadIdx.x >> 6);
    int lane = threadIdx.x & 63;
    float acc[NEXP] = {0.f, 0.f, 0.f, 0.f, 0.f, 0.f, 0.f, 0.f};
    const float* xr = x + (long)t * DIM;
    for (int d = lane; d < DIM; d += 64) {
        float xv = xr[d];
        float4 w0 = *(const float4*)(Wg + d * NEXP);
        float4 w1 = *(const float4*)(Wg + d * NEXP + 4);
        acc[0] += xv * w0.x; acc[1] += xv * w0.y; acc[2] += xv * w0.z; acc[3] += xv * w0.w;
        acc[4] += xv * w1.x; acc[5] += xv * w1.y; acc[6] += xv * w1.z; acc[7] += xv * w1.w;
    }
#pragma unroll
    for (int e = 0; e < NEXP; e++)
#pragma unroll
        for (int off = 32; off; off >>= 1)
            acc[e] += __shfl_xor(acc[e], off);
    if (lane == 0) {
        float m = acc[0];
#pragma unroll
        for (int e = 1; e < NEXP; e++) m = fmaxf(m, acc[e]);
        float p[NEXP], s = 0.f;
#pragma unroll
        for (int e = 0; e < NEXP; e++) { p[e] = expf(acc[e] - m); s += p[e]; }
        float inv = 1.f / s;
#pragma unroll
        for (int e = 0; e < NEXP; e++) p[e] *= inv;
        int i1 = 0;
#pragma unroll
        for (int e = 1; e < NEXP; e++) if (p[e] > p[i1]) i1 = e;          // strict > : lowest idx on tie
        int i2 = (i1 == 0) ? 1 : 0;
#pragma unroll
        for (int e = 0; e < NEXP; e++) if (e != i1 && p[e] > p[i2]) i2 = e;
        float* cr = c + (long)t * NEXP;
#pragma unroll
        for (int e = 0; e < NEXP; e++)
            cr[e] = (e == i1) ? p[i1] : ((e == i2) ? p[i2] : 0.f);
    }
}

// ---------------------------------------------------------------------------
// Fused gate+up SwiGLU GEMM. Block tile 128(rows=tokens) x 64(cols), BK=32,
// 256 threads = 4 waves in 2x2, wave tile 64x32, 16x16x32 bf16 MFMA.
// Computes G = X*Wg, U = X*Wu (shared A tile), epilogue silu(G)*U*c -> H bf16.
// expertMode: z picks expert; weights offset z*DEXP*DIM; H col offset DSH+z*DEXP.
// ---------------------------------------------------------------------------
__global__ __launch_bounds__(256) void gemm_gu(const bf16* __restrict__ X,
                                               const bf16* __restrict__ WgT,  // [M,DIM]
                                               const bf16* __restrict__ WuT,  // [M,DIM]
                                               const float* __restrict__ cbuf,
                                               bf16* __restrict__ H,
                                               int expertMode) {
    __shared__ __align__(16) bf16 sA[128 * 32];
    __shared__ __align__(16) bf16 sBg[64 * 32];
    __shared__ __align__(16) bf16 sBu[64 * 32];

    const int e = blockIdx.z;
    const long wOff = expertMode ? (long)e * (DEXP * DIM) : 0;
    const bf16* wg = WgT + wOff;
    const bf16* wu = WuT + wOff;
    const int colOff = expertMode ? (DSH + e * DEXP) : 0;
    const int bcol0 = blockIdx.x * 64;
    const int row0 = blockIdx.y * 128;
    const int tid = threadIdx.x;
    const int wave = tid >> 6, lane = tid & 63;
    const int wr = wave >> 1, wc = wave & 1;
    const int q = lane >> 4, l15 = lane & 15;

    floatx4 accG[4][2], accU[4][2];
    const floatx4 z4 = {0.f, 0.f, 0.f, 0.f};
#pragma unroll
    for (int i = 0; i < 4; i++)
#pragma unroll
        for (int j = 0; j < 2; j++) { accG[i][j] = z4; accU[i][j] = z4; }

    for (int k0 = 0; k0 < DIM; k0 += 32) {
        // stage A tile [128][32] : 512 16B chunks, 2/thread
#pragma unroll
        for (int it = 0; it < 2; it++) {
            int ch = it * 256 + tid;
            int r = ch >> 2, c4 = ch & 3;
            *(bf16x8*)(sA + r * 32 + c4 * 8) =
                *(const bf16x8*)(X + (long)(row0 + r) * DIM + k0 + c4 * 8);
        }
        // stage Bg/Bu tiles [64][32] : 256 chunks each, 1/thread
        {
            int r = tid >> 2, c4 = tid & 3;
            long gi = (long)(bcol0 + r) * DIM + k0 + c4 * 8;
            *(bf16x8*)(sBg + r * 32 + c4 * 8) = *(const bf16x8*)(wg + gi);
            *(bf16x8*)(sBu + r * 32 + c4 * 8) = *(const bf16x8*)(wu + gi);
        }
        __syncthreads();

        bf16x8 af[4], bg[2], bu[2];
#pragma unroll
        for (int rt = 0; rt < 4; rt++)
            af[rt] = *(const bf16x8*)(sA + (wr * 64 + rt * 16 + l15) * 32 + q * 8);
#pragma unroll
        for (int ct = 0; ct < 2; ct++) {
            int cb = (wc * 32 + ct * 16 + l15) * 32 + q * 8;
            bg[ct] = *(const bf16x8*)(sBg + cb);
            bu[ct] = *(const bf16x8*)(sBu + cb);
        }
#pragma unroll
        for (int rt = 0; rt < 4; rt++)
#pragma unroll
            for (int ct = 0; ct < 2; ct++) {
                accG[rt][ct] = __builtin_amdgcn_mfma_f32_16x16x32_bf16(af[rt], bg[ct], accG[rt][ct], 0, 0, 0);
                accU[rt][ct] = __builtin_amdgcn_mfma_f32_16x16x32_bf16(af[rt], bu[ct], accU[rt][ct], 0, 0, 0);
            }
        __syncthreads();
    }

    // epilogue: silu(g)*u*c -> H   (C/D layout: col=lane&15, row=q*4+reg)
    float cv[4][4];
#pragma unroll
    for (int rt = 0; rt < 4; rt++)
#pragma unroll
        for (int r = 0; r < 4; r++) {
            int n = row0 + wr * 64 + rt * 16 + q * 4 + r;
            cv[rt][r] = expertMode ? cbuf[(long)n * NEXP + e] : 1.0f;
        }
#pragma unroll
    for (int rt = 0; rt < 4; rt++)
#pragma unroll
        for (int ct = 0; ct < 2; ct++)
#pragma unroll
            for (int r = 0; r < 4; r++) {
                int n = row0 + wr * 64 + rt * 16 + q * 4 + r;
                int mc = bcol0 + wc * 32 + ct * 16 + l15;
                float g = accG[rt][ct][r];
                float u = accU[rt][ct][r];
                float h = (g / (1.f + __expf(-g))) * u * cv[rt][r];
                H[(long)n * KH + colOff + mc] = __float2bfloat16(h);
            }
}

// ---------------------------------------------------------------------------
// Down GEMM: out[2048,1024] = H[2048,5120] * Bd[5120,1024], B given transposed
// [1024,5120]. Same tiling as gemm_gu but single B. fp32 output (shared+routed
// combine is implicit in the K concatenation).
// ---------------------------------------------------------------------------
__global__ __launch_bounds__(256) void gemm_down(const bf16* __restrict__ A,
                                                 const bf16* __restrict__ BT,
                                                 float* __restrict__ out) {
    __shared__ __align__(16) bf16 sA[128 * 32];
    __shared__ __align__(16) bf16 sB[64 * 32];
    const int bcol0 = blockIdx.x * 64;
    const int row0 = blockIdx.y * 128;
    const int tid = threadIdx.x;
    const int wave = tid >> 6, lane = tid & 63;
    const int wr = wave >> 1, wc = wave & 1;
    const int q = lane >> 4, l15 = lane & 15;

    floatx4 acc[4][2];
    const floatx4 z4 = {0.f, 0.f, 0.f, 0.f};
#pragma unroll
    for (int i = 0; i < 4; i++)
#pragma unroll
        for (int j = 0; j < 2; j++) acc[i][j] = z4;

    for (int k0 = 0; k0 < KH; k0 += 32) {
#pragma unroll
        for (int it = 0; it < 2; it++) {
            int ch = it * 256 + tid;
            int r = ch >> 2, c4 = ch & 3;
            *(bf16x8*)(sA + r * 32 + c4 * 8) =
                *(const bf16x8*)(A + (long)(row0 + r) * KH + k0 + c4 * 8);
        }
        {
            int r = tid >> 2, c4 = tid & 3;
            *(bf16x8*)(sB + r * 32 + c4 * 8) =
                *(const bf16x8*)(BT + (long)(bcol0 + r) * KH + k0 + c4 * 8);
        }
        __syncthreads();

        bf16x8 af[4], bb[2];
#pragma unroll
        for (int rt = 0; rt < 4; rt++)
            af[rt] = *(const bf16x8*)(sA + (wr * 64 + rt * 16 + l15) * 32 + q * 8);
#pragma unroll
        for (int ct = 0; ct < 2; ct++)
            bb[ct] = *(const bf16x8*)(sB + (wc * 32 + ct * 16 + l15) * 32 + q * 8);
#pragma unroll
        for (int rt = 0; rt < 4; rt++)
#pragma unroll
            for (int ct = 0; ct < 2; ct++)
                acc[rt][ct] = __builtin_amdgcn_mfma_f32_16x16x32_bf16(af[rt], bb[ct], acc[rt][ct], 0, 0, 0);
        __syncthreads();
    }

#pragma unroll
    for (int rt = 0; rt < 4; rt++)
#pragma unroll
        for (int ct = 0; ct < 2; ct++)
#pragma unroll
            for (int r = 0; r < 4; r++) {
                int n = row0 + wr * 64 + rt * 16 + q * 4 + r;
                int mc = bcol0 + wc * 32 + ct * 16 + l15;
                out[(long)n * DIM + mc] = acc[rt][ct][r];
            }
}

// ---------------------------------------------------------------------------
extern "C" void kernel_launch(void* const* d_in, const int* in_sizes, int n_in,
                              void* d_out, int out_size, void* d_ws, size_t ws_size,
                              hipStream_t stream) {
    const float* x    = (const float*)d_in[0];
    const float* W_g  = (const float*)d_in[1];
    const float* Wg_e = (const float*)d_in[2];
    const float* Wu_e = (const float*)d_in[3];
    const float* Wd_e = (const float*)d_in[4];
    const float* Wg_s = (const float*)d_in[5];
    const float* Wu_s = (const float*)d_in[6];
    const float* Wd_s = (const float*)d_in[7];
    float* out = (float*)d_out;

    // workspace layout (bf16 unless noted): ~56.7 MB total
    bf16* Xb   = (bf16*)d_ws;                          // [2048,1024]
    bf16* WgsT = Xb   + (size_t)NTOK * DIM;            // [1024,1024]
    bf16* WusT = WgsT + (size_t)DSH * DIM;             // [1024,1024]
    bf16* WgeT = WusT + (size_t)DSH * DIM;             // [8,512,1024]
    bf16* WueT = WgeT + (size_t)NEXP * DEXP * DIM;     // [8,512,1024]
    bf16* BdT  = WueT + (size_t)NEXP * DEXP * DIM;     // [1024,5120]
    bf16* Hbuf = BdT  + (size_t)DIM * KH;              // [2048,5120]
    float* Cbuf = (float*)(Hbuf + (size_t)NTOK * KH);  // [2048,8] fp32

    // 1) casts / transposes
    cast_x_kernel<<<(NTOK * DIM / 4 + 255) / 256, 256, 0, stream>>>(x, Xb, NTOK * DIM / 4);
    tcast<<<dim3(32, 32, 1), 256, 0, stream>>>(Wg_s, WgsT, 1024, 1024, 0, 0, 0, DIM);
    tcast<<<dim3(32, 32, 1), 256, 0, stream>>>(Wu_s, WusT, 1024, 1024, 0, 0, 0, DIM);
    tcast<<<dim3(16, 32, NEXP), 256, 0, stream>>>(Wg_e, WgeT, 1024, 512,
                                                  (long)1024 * 512, 0, (long)512 * 1024, DIM);
    tcast<<<dim3(16, 32, NEXP), 256, 0, stream>>>(Wu_e, WueT, 1024, 512,
                                                  (long)1024 * 512, 0, (long)512 * 1024, DIM);
    tcast<<<dim3(32, 32, 1), 256, 0, stream>>>(Wd_s, BdT, 1024, 1024, 0, 0, 0, KH);
    tcast<<<dim3(32, 16, NEXP), 256, 0, stream>>>(Wd_e, BdT, 512, 1024,
                                                  (long)512 * 1024, 1024, 512, KH);
    // 2) gating -> combine weights c
    gate_kernel<<<NTOK / 4, 256, 0, stream>>>(x, W_g, Cbuf);
    // 3) shared expert gate/up (H cols 0..1023)
    gemm_gu<<<dim3(DSH / 64, NTOK / 128, 1), 256, 0, stream>>>(Xb, WgsT, WusT, nullptr, Hbuf, 0);
    // 4) routed experts gate/up, dense with c-weighting (H cols 1024..5119)
    gemm_gu<<<dim3(DEXP / 64, NTOK / 128, NEXP), 256, 0, stream>>>(Xb, WgeT, WueT, Cbuf, Hbuf, 1);
    // 5) down-proj over concatenated K=5120 -> fp32 out (= shared + routed)
    gemm_down<<<dim3(DIM / 64, NTOK / 128, 1), 256, 0, stream>>>(Hbuf, BdT, out);
}

// Round 2
// 241.914 us; speedup vs baseline: 1.1999x; 1.1999x over previous
//
#include <hip/hip_runtime.h>
#include <hip/hip_bf16.h>

#define NTOK 2048
#define DIM  1024
#define DEXP 512
#define NEXP 8
#define DSH  1024          // shared expert width
#define KH   5120          // DSH + NEXP*DEXP

typedef __hip_bfloat16 bf16;
typedef __attribute__((ext_vector_type(8))) short bf16x8;
typedef __attribute__((ext_vector_type(4))) float floatx4;

// async global->LDS, 16B per lane. LDS dest = wave-uniform base + lane*16.
__device__ __forceinline__ void gl_lds16(const bf16* g, bf16* l) {
    __builtin_amdgcn_global_load_lds(
        (const __attribute__((address_space(1))) void*)g,
        (__attribute__((address_space(3))) void*)l, 16, 0, 0);
}

// ---------------------------------------------------------------------------
// fp32 -> bf16 flat cast (x)
// ---------------------------------------------------------------------------
__global__ __launch_bounds__(256) void cast_x_kernel(const float* __restrict__ src,
                                                     bf16* __restrict__ dst, int n4) {
    int i = blockIdx.x * 256 + threadIdx.x;
    if (i >= n4) return;
    float4 v = ((const float4*)src)[i];
    struct B4 { bf16 a, b, c, d; };
    B4 o{__float2bfloat16(v.x), __float2bfloat16(v.y),
         __float2bfloat16(v.z), __float2bfloat16(v.w)};
    ((B4*)dst)[i] = o;
}

// ---------------------------------------------------------------------------
// One dispatch packing ALL weights (transpose fp32->bf16) into:
//   Bg [5120][1024]  gate:  rows 0..1023 = Wg_s^T ; rows 1024+e*512+h = Wg_e[e][:,h]
//   Bu [5120][1024]  up:    same from Wu_s / Wu_e
//   Bd [1024][5120]  down:  cols 0..1023 = Wd_s^T ; cols 1024+e*512+k = Wd_e[e][k][:]
// 32x32 tiles via LDS. Region decode from blockIdx.x (all sizes pow2).
// ---------------------------------------------------------------------------
__global__ __launch_bounds__(256) void pack_weights(
        const float* __restrict__ Wg_s, const float* __restrict__ Wu_s,
        const float* __restrict__ Wg_e, const float* __restrict__ Wu_e,
        const float* __restrict__ Wd_s, const float* __restrict__ Wd_e,
        bf16* __restrict__ Bg, bf16* __restrict__ Bu, bf16* __restrict__ Bd) {
    __shared__ float t[32][33];
    int b = blockIdx.x;
    const float* src; bf16* dst; int C; long dstStride, dstBase; int tilesX;
    if (b < 1024)       { src = Wg_s; dst = Bg; C = 1024; dstStride = 1024; dstBase = 0; tilesX = 32; }
    else if (b < 2048)  { b -= 1024; src = Wu_s; dst = Bu; C = 1024; dstStride = 1024; dstBase = 0; tilesX = 32; }
    else if (b < 6144)  { b -= 2048; int z = b >> 9; b &= 511;
                          src = Wg_e + (long)z * DIM * DEXP; dst = Bg; C = 512;
                          dstStride = 1024; dstBase = (long)(DSH + z * DEXP) * 1024; tilesX = 16; }
    else if (b < 10240) { b -= 6144; int z = b >> 9; b &= 511;
                          src = Wu_e + (long)z * DIM * DEXP; dst = Bu; C = 512;
                          dstStride = 1024; dstBase = (long)(DSH + z * DEXP) * 1024; tilesX = 16; }
    else if (b < 11264) { b -= 10240; src = Wd_s; dst = Bd; C = 1024; dstStride = KH; dstBase = 0; tilesX = 32; }
    else                { b -= 11264; int z = b >> 9; b &= 511;
                          src = Wd_e + (long)z * DEXP * DIM; dst = Bd; C = 1024;
                          dstStride = KH; dstBase = DSH + (long)z * DEXP; tilesX = 32; }
    int tileX = b & (tilesX - 1), tileY = b / tilesX;
    int c0 = tileX * 32, r0 = tileY * 32;
    int tx = threadIdx.x & 31, ty = threadIdx.x >> 5;
#pragma unroll
    for (int i = 0; i < 4; i++)
        t[ty + i * 8][tx] = src[(long)(r0 + ty + i * 8) * C + c0 + tx];
    __syncthreads();
#pragma unroll
    for (int i = 0; i < 4; i++)
        dst[dstBase + (long)(c0 + ty + i * 8) * dstStride + r0 + tx] =
            __float2bfloat16(t[tx][ty + i * 8]);
}

// ---------------------------------------------------------------------------
// Gating: one wave per token, fp32 throughout so top-2 matches reference.
// ---------------------------------------------------------------------------
__global__ __launch_bounds__(256) void gate_kernel(const float* __restrict__ x,
                                                   const float* __restrict__ Wg,
                                                   float* __restrict__ c) {
    int t = blockIdx.x * 4 + (threadIdx.x >> 6);
    int lane = threadIdx.x & 63;
    float acc[NEXP] = {0.f, 0.f, 0.f, 0.f, 0.f, 0.f, 0.f, 0.f};
    const float* xr = x + (long)t * DIM;
    for (int d = lane; d < DIM; d += 64) {
        float xv = xr[d];
        float4 w0 = *(const float4*)(Wg + d * NEXP);
        float4 w1 = *(const float4*)(Wg + d * NEXP + 4);
        acc[0] += xv * w0.x; acc[1] += xv * w0.y; acc[2] += xv * w0.z; acc[3] += xv * w0.w;
        acc[4] += xv * w1.x; acc[5] += xv * w1.y; acc[6] += xv * w1.z; acc[7] += xv * w1.w;
    }
#pragma unroll
    for (int e = 0; e < NEXP; e++)
#pragma unroll
        for (int off = 32; off; off >>= 1)
            acc[e] += __shfl_xor(acc[e], off);
    if (lane == 0) {
        float m = acc[0];
#pragma unroll
        for (int e = 1; e < NEXP; e++) m = fmaxf(m, acc[e]);
        float p[NEXP], s = 0.f;
#pragma unroll
        for (int e = 0; e < NEXP; e++) { p[e] = expf(acc[e] - m); s += p[e]; }
        float inv = 1.f / s;
#pragma unroll
        for (int e = 0; e < NEXP; e++) p[e] *= inv;
        int i1 = 0;
#pragma unroll
        for (int e = 1; e < NEXP; e++) if (p[e] > p[i1]) i1 = e;
        int i2 = (i1 == 0) ? 1 : 0;
#pragma unroll
        for (int e = 0; e < NEXP; e++) if (e != i1 && p[e] > p[i2]) i2 = e;
        float* cr = c + (long)t * NEXP;
#pragma unroll
        for (int e = 0; e < NEXP; e++)
            cr[e] = (e == i1) ? p[i1] : ((e == i2) ? p[i2] : 0.f);
    }
}

// ---------------------------------------------------------------------------
// Packed gate+up SwiGLU GEMM over N=5120 columns (shared cols 0..1023, then
// 512/expert). Tile 128(tok) x 64(col), BK=32, 4 waves (2x2), wave 64x32 for
// BOTH G and U; async LDS staging; epilogue silu(g)*u*c -> H bf16.
// ---------------------------------------------------------------------------
__global__ __launch_bounds__(256) void gemm_gu(const bf16* __restrict__ X,
                                               const bf16* __restrict__ Bg,
                                               const bf16* __restrict__ Bu,
                                               const float* __restrict__ cbuf,
                                               bf16* __restrict__ H) {
    __shared__ __align__(16) bf16 sA[128 * 32];
    __shared__ __align__(16) bf16 sBg[64 * 32];
    __shared__ __align__(16) bf16 sBu[64 * 32];

    const int bcol0 = blockIdx.x * 64;
    const int row0 = blockIdx.y * 128;
    const int tid = threadIdx.x;
    const int wave = tid >> 6, lane = tid & 63;
    const int wr = wave >> 1, wc = wave & 1;
    const int q = lane >> 4, l15 = lane & 15;
    const int ch0 = wave * 64 + lane;
    const int chA_r = ch0 >> 2, chA_c = ch0 & 3;   // B tiles: 1 chunk/thread
    const int ch1 = 256 + ch0;

    floatx4 accG[4][2], accU[4][2];
    const floatx4 z4 = {0.f, 0.f, 0.f, 0.f};
#pragma unroll
    for (int i = 0; i < 4; i++)
#pragma unroll
        for (int j = 0; j < 2; j++) { accG[i][j] = z4; accU[i][j] = z4; }

    for (int k0 = 0; k0 < DIM; k0 += 32) {
        // A [128][32] : 512 chunks, 2/thread
        gl_lds16(X + (long)(row0 + chA_r) * DIM + k0 + chA_c * 8,
                 sA + (long)(wave * 64) * 8);
        gl_lds16(X + (long)(row0 + (ch1 >> 2)) * DIM + k0 + (ch1 & 3) * 8,
                 sA + (long)(256 + wave * 64) * 8);
        // Bg/Bu [64][32] : 256 chunks, 1/thread
        gl_lds16(Bg + (long)(bcol0 + chA_r) * DIM + k0 + chA_c * 8,
                 sBg + (long)(wave * 64) * 8);
        gl_lds16(Bu + (long)(bcol0 + chA_r) * DIM + k0 + chA_c * 8,
                 sBu + (long)(wave * 64) * 8);
        __syncthreads();

        bf16x8 af[4], bg[2], bu[2];
#pragma unroll
        for (int rt = 0; rt < 4; rt++)
            af[rt] = *(const bf16x8*)(sA + (wr * 64 + rt * 16 + l15) * 32 + q * 8);
#pragma unroll
        for (int ct = 0; ct < 2; ct++) {
            int cb = (wc * 32 + ct * 16 + l15) * 32 + q * 8;
            bg[ct] = *(const bf16x8*)(sBg + cb);
            bu[ct] = *(const bf16x8*)(sBu + cb);
        }
#pragma unroll
        for (int rt = 0; rt < 4; rt++)
#pragma unroll
            for (int ct = 0; ct < 2; ct++) {
                accG[rt][ct] = __builtin_amdgcn_mfma_f32_16x16x32_bf16(af[rt], bg[ct], accG[rt][ct], 0, 0, 0);
                accU[rt][ct] = __builtin_amdgcn_mfma_f32_16x16x32_bf16(af[rt], bu[ct], accU[rt][ct], 0, 0, 0);
            }
        __syncthreads();
    }

    // epilogue: silu(g)*u*c -> H  (C/D layout: col=lane&15, row=q*4+reg)
    const int isExpert = (bcol0 >= DSH);
    const int e = isExpert ? ((bcol0 - DSH) >> 9) : 0;
    float cv[4][4];
#pragma unroll
    for (int rt = 0; rt < 4; rt++)
#pragma unroll
        for (int r = 0; r < 4; r++) {
            int n = row0 + wr * 64 + rt * 16 + q * 4 + r;
            cv[rt][r] = isExpert ? cbuf[(long)n * NEXP + e] : 1.0f;
        }
#pragma unroll
    for (int rt = 0; rt < 4; rt++)
#pragma unroll
        for (int ct = 0; ct < 2; ct++)
#pragma unroll
            for (int r = 0; r < 4; r++) {
                int n = row0 + wr * 64 + rt * 16 + q * 4 + r;
                int mc = bcol0 + wc * 32 + ct * 16 + l15;
                float g = accG[rt][ct][r];
                float u = accU[rt][ct][r];
                float h = (g / (1.f + __expf(-g))) * u * cv[rt][r];
                H[(long)n * KH + mc] = __float2bfloat16(h);
            }
}

// ---------------------------------------------------------------------------
// Down GEMM, split-K=4: out[2048,1024] += H[2048,5120] * Bd^T. Tile 128x128,
// 4 waves (2x2) each 64x64, BK=32, async staging, fp32 atomicAdd epilogue.
// ---------------------------------------------------------------------------
__global__ __launch_bounds__(256) void gemm_down(const bf16* __restrict__ A,
                                                 const bf16* __restrict__ BT,
                                                 float* __restrict__ out) {
    __shared__ __align__(16) bf16 sA[128 * 32];
    __shared__ __align__(16) bf16 sB[128 * 32];
    const int col0 = blockIdx.x * 128;
    const int row0 = blockIdx.y * 128;
    const int kbase = blockIdx.z * (KH / 4);
    const int tid = threadIdx.x;
    const int wave = tid >> 6, lane = tid & 63;
    const int wr = wave >> 1, wc = wave & 1;
    const int q = lane >> 4, l15 = lane & 15;
    const int ch0 = wave * 64 + lane;
    const int ch1 = 256 + ch0;
    const int r0c = ch0 >> 2, c0c = ch0 & 3;
    const int r1c = ch1 >> 2, c1c = ch1 & 3;

    floatx4 acc[4][4];
    const floatx4 z4 = {0.f, 0.f, 0.f, 0.f};
#pragma unroll
    for (int i = 0; i < 4; i++)
#pragma unroll
        for (int j = 0; j < 4; j++) acc[i][j] = z4;

    for (int k0 = kbase; k0 < kbase + KH / 4; k0 += 32) {
        gl_lds16(A + (long)(row0 + r0c) * KH + k0 + c0c * 8, sA + (long)(wave * 64) * 8);
        gl_lds16(A + (long)(row0 + r1c) * KH + k0 + c1c * 8, sA + (long)(256 + wave * 64) * 8);
        gl_lds16(BT + (long)(col0 + r0c) * KH + k0 + c0c * 8, sB + (long)(wave * 64) * 8);
        gl_lds16(BT + (long)(col0 + r1c) * KH + k0 + c1c * 8, sB + (long)(256 + wave * 64) * 8);
        __syncthreads();

        bf16x8 af[4], bb[4];
#pragma unroll
        for (int rt = 0; rt < 4; rt++)
            af[rt] = *(const bf16x8*)(sA + (wr * 64 + rt * 16 + l15) * 32 + q * 8);
#pragma unroll
        for (int ct = 0; ct < 4; ct++)
            bb[ct] = *(const bf16x8*)(sB + (wc * 64 + ct * 16 + l15) * 32 + q * 8);
#pragma unroll
        for (int rt = 0; rt < 4; rt++)
#pragma unroll
            for (int ct = 0; ct < 4; ct++)
                acc[rt][ct] = __builtin_amdgcn_mfma_f32_16x16x32_bf16(af[rt], bb[ct], acc[rt][ct], 0, 0, 0);
        __syncthreads();
    }

#pragma unroll
    for (int rt = 0; rt < 4; rt++)
#pragma unroll
        for (int ct = 0; ct < 4; ct++)
#pragma unroll
            for (int r = 0; r < 4; r++) {
                int n = row0 + wr * 64 + rt * 16 + q * 4 + r;
                int mc = col0 + wc * 64 + ct * 16 + l15;
                atomicAdd(out + (long)n * DIM + mc, acc[rt][ct][r]);
            }
}

// ---------------------------------------------------------------------------
extern "C" void kernel_launch(void* const* d_in, const int* in_sizes, int n_in,
                              void* d_out, int out_size, void* d_ws, size_t ws_size,
                              hipStream_t stream) {
    const float* x    = (const float*)d_in[0];
    const float* W_g  = (const float*)d_in[1];
    const float* Wg_e = (const float*)d_in[2];
    const float* Wu_e = (const float*)d_in[3];
    const float* Wd_e = (const float*)d_in[4];
    const float* Wg_s = (const float*)d_in[5];
    const float* Wu_s = (const float*)d_in[6];
    const float* Wd_s = (const float*)d_in[7];
    float* out = (float*)d_out;

    bf16* Xb   = (bf16*)d_ws;                          // [2048,1024]
    bf16* Bg   = Xb + (size_t)NTOK * DIM;              // [5120,1024]
    bf16* Bu   = Bg + (size_t)KH * DIM;                // [5120,1024]
    bf16* Bd   = Bu + (size_t)KH * DIM;                // [1024,5120]
    bf16* Hbuf = Bd + (size_t)DIM * KH;                // [2048,5120]
    float* Cbuf = (float*)(Hbuf + (size_t)NTOK * KH);  // [2048,8]

    hipMemsetAsync(out, 0, (size_t)NTOK * DIM * sizeof(float), stream);
    cast_x_kernel<<<(NTOK * DIM / 4 + 255) / 256, 256, 0, stream>>>(x, Xb, NTOK * DIM / 4);
    pack_weights<<<15360, 256, 0, stream>>>(Wg_s, Wu_s, Wg_e, Wu_e, Wd_s, Wd_e, Bg, Bu, Bd);
    gate_kernel<<<NTOK / 4, 256, 0, stream>>>(x, W_g, Cbuf);
    gemm_gu<<<dim3(KH / 64, NTOK / 128), 256, 0, stream>>>(Xb, Bg, Bu, Cbuf, Hbuf);
    gemm_down<<<dim3(DIM / 128, NTOK / 128, 4), 256, 0, stream>>>(Hbuf, Bd, out);
}